// Round 3
// baseline (1085.582 us; speedup 1.0000x reference)
//
#include <hip/hip_runtime.h>
#include <cstdint>
#include <cstddef>

#define MARGIN 0.26f

typedef _Float16 f16;
typedef _Float16 f16x4 __attribute__((ext_vector_type(4)));
typedef _Float16 f16x8 __attribute__((ext_vector_type(8)));
typedef float    f32x4 __attribute__((ext_vector_type(4)));
typedef unsigned int u32;

// async global->LDS, 16B/lane; LDS dest = uniform base + lane*16
__device__ __forceinline__ void gl_lds16(const void* g, void* l) {
  auto gp = (const __attribute__((address_space(1))) uint32_t*)(g);
  auto lp = (__attribute__((address_space(3))) uint32_t*)(l);
  __builtin_amdgcn_global_load_lds(gp, lp, 16, 0, 0);
}

__device__ __forceinline__ void ins4(u32 v, u32& a, u32& b, u32& c, u32& d) {
  if (v > a)      { d = c; c = b; b = a; a = v; }
  else if (v > b) { d = c; c = b; b = v; }
  else if (v > c) { d = c; c = v; }
  else if (v > d) { d = v; }
}

// ---------------------------------------------------------------------------
// prep: block = (t, cgrp of 64 cls), 512 thr. Coalesced 128B-segment reads of
// W, LDS frag assembly, 1KB-contiguous frag-major writes to Wh, direct wsq.
// Wh frag (t,ch,kt,fh) at ((((t*2+ch)*32+kt)*16)+fh)*512 f16; within a frag
// lane ln=q*16+m holds W[cls = ch*256+fh*16+m][k = kt*32+q*8+j] at ln*8+j.
// ---------------------------------------------------------------------------
__global__ __launch_bounds__(512) void prep_w(const float* __restrict__ W,
                                              f16* __restrict__ Wh,
                                              float* __restrict__ wsq) {
  __shared__ __align__(16) f16 sF[32 * 512];   // 32 frags x 1KB
  const int bx = blockIdx.x;
  const int t = bx >> 3, cgrp = bx & 7;
  const int tid = threadIdx.x;
  const int r = tid >> 3, i = tid & 7;         // r: local cls 0..63
  const int c = cgrp * 64 + r;
  const float* wr = W + ((size_t)t * 512 + c) * 1024;
  const int m = r & 15, fct = r >> 4;
  const int q = i >> 1, jj = (i & 1) * 4;
  const int ch = cgrp >> 2, fhb = (cgrp & 3) * 4;
  const int wv = tid >> 6, ln = tid & 63;
  float ssum = 0.f;
  for (int kq = 0; kq < 4; ++kq) {
    if (kq) __syncthreads();
#pragma unroll
    for (int j = 0; j < 8; ++j) {
      // instr j: lanes (r,i) -> 8 rows x 128B contiguous segments
      float4 x = *(const float4*)(wr + kq * 256 + j * 32 + i * 4);
      ssum += x.x * x.x + x.y * x.y + x.z * x.z + x.w * x.w;
      f16x4 hv;
      hv.x = (f16)x.x; hv.y = (f16)x.y; hv.z = (f16)x.z; hv.w = (f16)x.w;
      int lf = j * 4 + fct;                    // local frag (kt-local j, fct)
      *(f16x4*)(sF + lf * 512 + (q * 16 + m) * 8 + jj) = hv;
    }
    __syncthreads();
#pragma unroll
    for (int ii = 0; ii < 4; ++ii) {           // copy out: wave-per-frag, 1KB
      int lf = wv * 4 + ii;
      int j = lf >> 2, fl = lf & 3;
      int kt = kq * 8 + j;
      size_t gfrag = (size_t)(((t * 2 + ch) * 32 + kt) * 16 + fhb + fl);
      *(f16x8*)(Wh + gfrag * 512 + ln * 8) = *(const f16x8*)(sF + lf * 512 + ln * 8);
    }
  }
  ssum += __shfl_down(ssum, 4, 8);
  ssum += __shfl_down(ssum, 2, 8);
  ssum += __shfl_down(ssum, 1, 8);
  if (i == 0) wsq[t * 512 + c] = 0.5f * ssum;
}

// ---------------------------------------------------------------------------
// Main: block = (t, 64 rows); 4 waves, each wave = all 64 rows x 64 cls.
// Two 256-cls halves processed sequentially (X re-read is L2-hot).
// BK=64, B staged via global_load_lds (32KB), X staged f16-hi in LDS.
// Single hi-pass MFMA; packed-u32 top-4 per half; margin gate; fp64 refine.
// ---------------------------------------------------------------------------
__global__ __launch_bounds__(256, 3) void gemm_argmax(
    const float* __restrict__ X, const float* __restrict__ W,
    const f16* __restrict__ Wh, const float* __restrict__ wsq,
    int* __restrict__ out) {
  __shared__ __align__(16) f16 sB[2 * 16 * 512];  // 32KB: 2 k-subs x 16 frags
  __shared__ __align__(16) f16 sX[64 * 72];       // 9KB, stride 72 (16B-aligned)
  __shared__ u32 wcand[64][4][4];
  __shared__ u32 hcand[64][2][4];
  __shared__ float swsq[256];
  __shared__ int amb_cnt;
  __shared__ int amb_list[64];

  const int tid = threadIdx.x;
  const int wv = tid >> 6, ln = tid & 63;
  const int m = ln & 15, q = ln >> 4;
  const int bx = blockIdx.x;
  const int t = bx >> 5, rb = bx & 31;
  const int row0 = rb * 64;
  const int r4 = tid >> 2, cseg = tid & 3;

  if (tid == 0) amb_cnt = 0;
  const float* xrow = X + ((size_t)t * 2048 + row0 + r4) * 1024;

  for (int ch = 0; ch < 2; ++ch) {
    __syncthreads();                    // prior-half epilogue done
    swsq[tid] = wsq[t * 512 + ch * 256 + tid];

    const f32x4 zero4 = {0.f, 0.f, 0.f, 0.f};
    f32x4 acc[4][4];
#pragma unroll
    for (int a = 0; a < 4; ++a)
#pragma unroll
      for (int b = 0; b < 4; ++b) acc[a][b] = zero4;

    const f16* WhB = Wh + ((size_t)(t * 2 + ch) * 32 * 16) * 512;

    for (int it = 0; it < 16; ++it) {
      __syncthreads();                  // sB/sX reuse guard
      // stage B: 32 frags x 1KB, 8 gl_lds per wave
      {
        const int s = wv & 1, fh0 = (wv >> 1) * 8;
        const f16* gB = WhB + ((size_t)((2 * it + s) * 16 + fh0)) * 512 + ln * 8;
        f16* lB = sB + (s * 16 + fh0) * 512;
#pragma unroll
        for (int ii = 0; ii < 8; ++ii)
          gl_lds16(gB + ii * 512, lB + ii * 512);
      }
      // stage X: hi-only f16; instr l: lanes cseg contiguous -> 64B/row segs
      {
        const float* xs = xrow + it * 64;
#pragma unroll
        for (int l = 0; l < 4; ++l) {
          float4 v = *(const float4*)(xs + l * 16 + cseg * 4);
          f16x4 h;
          h.x = (f16)v.x; h.y = (f16)v.y; h.z = (f16)v.z; h.w = (f16)v.w;
          *(f16x4*)(sX + r4 * 72 + l * 16 + cseg * 4) = h;
        }
      }
      __syncthreads();
      // compute: 2 k-subs x 4rt x 4ct MFMA
#pragma unroll
      for (int s = 0; s < 2; ++s) {
        f16x8 a[4], b[4];
#pragma unroll
        for (int rt = 0; rt < 4; ++rt)
          a[rt] = *(const f16x8*)(sX + (rt * 16 + m) * 72 + s * 32 + q * 8);
#pragma unroll
        for (int ct = 0; ct < 4; ++ct)
          b[ct] = *(const f16x8*)(sB + (s * 16 + wv * 4 + ct) * 512 + ln * 8);
#pragma unroll
        for (int rt = 0; rt < 4; ++rt)
#pragma unroll
          for (int ct = 0; ct < 4; ++ct)
            acc[rt][ct] = __builtin_amdgcn_mfma_f32_16x16x32_f16(
                a[rt], b[ct], acc[rt][ct], 0, 0, 0);
      }
    }

    // epilogue: C/D col=lane&15, row=q*4+reg. Packed keys, top-4 per wave.
#pragma unroll
    for (int rt = 0; rt < 4; ++rt) {
#pragma unroll
      for (int rr = 0; rr < 4; ++rr) {
        u32 t0 = 0, t1 = 0, t2 = 0, t3 = 0;
#pragma unroll
        for (int ct = 0; ct < 4; ++ct) {
          int lc = wv * 64 + ct * 16 + m;
          float v = acc[rt][ct][rr] - swsq[lc];
          float vq = fminf(fmaxf((v + 1024.f) * 2048.f, 0.f), 4194303.f);
          u32 key = (((u32)vq) << 9) | (u32)(511 - (ch * 256 + lc));
          ins4(key, t0, t1, t2, t3);
        }
#pragma unroll
        for (int off = 1; off < 16; off <<= 1) {
          u32 s0 = __shfl_xor(t0, off), s1 = __shfl_xor(t1, off);
          u32 s2 = __shfl_xor(t2, off), s3 = __shfl_xor(t3, off);
          ins4(s0, t0, t1, t2, t3); ins4(s1, t0, t1, t2, t3);
          ins4(s2, t0, t1, t2, t3); ins4(s3, t0, t1, t2, t3);
        }
        if (m == 0) {
          int row = rt * 16 + q * 4 + rr;
          wcand[row][wv][0] = t0; wcand[row][wv][1] = t1;
          wcand[row][wv][2] = t2; wcand[row][wv][3] = t3;
        }
      }
    }
    __syncthreads();
    if (tid < 64) {                      // merge 4 waves -> half top-4
      u32 t0 = 0, t1 = 0, t2 = 0, t3 = 0;
#pragma unroll
      for (int w = 0; w < 4; ++w)
#pragma unroll
        for (int k = 0; k < 4; ++k) ins4(wcand[tid][w][k], t0, t1, t2, t3);
      hcand[tid][ch][0] = t0; hcand[tid][ch][1] = t1;
      hcand[tid][ch][2] = t2; hcand[tid][ch][3] = t3;
    }
  }
  __syncthreads();

  // gate
  if (tid < 64) {
    u32 best = 0, second = 0;
#pragma unroll
    for (int g = 0; g < 2; ++g)
#pragma unroll
      for (int k = 0; k < 4; ++k) {
        u32 v = hcand[tid][g][k];
        if (v > best) { second = best; best = v; }
        else if (v > second) second = v;
      }
    float v1 = (float)(best >> 9) * (1.f / 2048.f);
    float v2 = (float)(second >> 9) * (1.f / 2048.f);
    if (v1 - v2 >= MARGIN) {
      out[(size_t)t * 2048 + row0 + tid] = 511 - (int)(best & 511);
    } else {
      int p = atomicAdd(&amb_cnt, 1);
      amb_list[p] = tid;
    }
  }
  __syncthreads();

  // fp64 refinement (expected ~1 row per ~2 blocks)
  int nA = amb_cnt;
  for (int a = wv; a < nA; a += 4) {
    int rl = amb_list[a];
    const float* xr = X + ((size_t)t * 2048 + row0 + rl) * 1024;
    double bestv = -1.0e300; int bidx = 0x7fffffff;
    for (int g = 0; g < 2; ++g) {
      for (int k = 0; k < 4; ++k) {
        int cidx = 511 - (int)(hcand[rl][g][k] & 511);
        const float* wr = W + ((size_t)t * 512 + cidx) * 1024;
        double sd = 0.0, sw = 0.0;
        for (int j = 0; j < 16; ++j) {
          float xv = xr[ln + 64 * j];
          float wv2 = wr[ln + 64 * j];
          sd += (double)xv * (double)wv2;
          sw += (double)wv2 * (double)wv2;
        }
#pragma unroll
        for (int off = 32; off > 0; off >>= 1) {
          sd += __shfl_xor(sd, off);
          sw += __shfl_xor(sw, off);
        }
        double sc = sd - 0.5 * sw;
        if (sc > bestv || (sc == bestv && cidx < bidx)) { bestv = sc; bidx = cidx; }
      }
    }
    if (ln == 0) out[(size_t)t * 2048 + row0 + rl] = bidx;
  }
}

extern "C" void kernel_launch(void* const* d_in, const int* in_sizes, int n_in,
                              void* d_out, int out_size, void* d_ws, size_t ws_size,
                              hipStream_t stream) {
  (void)in_sizes; (void)n_in; (void)out_size;
  const float* X = (const float*)d_in[0];
  const float* W = (const float*)d_in[1];
  // temp (d_in[2]) is argmax-invariant; unused.
  const size_t wh_bytes = (size_t)32 * 512 * 1024 * sizeof(f16);   // 32 MiB
  const size_t need = wh_bytes + (size_t)32 * 512 * sizeof(float); // +64KB (proven fit)
  if (ws_size < need) return;
  f16*   Wh  = (f16*)d_ws;
  float* wsq = (float*)((char*)d_ws + wh_bytes);
  int*   out = (int*)d_out;
  prep_w<<<32 * 8, 512, 0, stream>>>(W, Wh, wsq);
  gemm_argmax<<<32 * 32, 256, 0, stream>>>(X, W, Wh, wsq, out);
}